// Round 10
// baseline (698.083 us; speedup 1.0000x reference)
//
#include <hip/hip_runtime.h>
#include <hip/hip_cooperative_groups.h>
#include <math.h>

namespace cg = cooperative_groups;

namespace {
constexpr int NB = 256;    // batch
constexpr int NR = 1152;   // routes
constexpr int NC = 10;     // output capsules
constexpr int NO = 16;     // output dim
constexpr int NI = 8;      // input dim
constexpr int K1 = NR * NI;   // 9216
constexpr int NN = NC * NO;   // 160
constexpr int KS = 36;        // GEMM1 split-K slices
constexpr int KC = K1 / KS;   // 256 -> 8 mfma per slice
constexpr int GRID = 512;     // 2 blocks/CU, all co-resident (cooperative)
}

using s16x8 = __attribute__((ext_vector_type(8))) short;
using f32x4 = __attribute__((ext_vector_type(4))) float;

__device__ __forceinline__ ushort f2bf(float f) {
    uint u = __float_as_uint(f);
    uint r = (u + 0x7FFFu + ((u >> 16) & 1u)) >> 16;
    return (ushort)r;
}

__global__ __launch_bounds__(256, 2) void k_fused(const float* __restrict__ x,
                                                  const float* __restrict__ W,
                                                  float* __restrict__ out,
                                                  float* __restrict__ bbuf,
                                                  float* __restrict__ spart,
                                                  ushort* __restrict__ xbf,
                                                  ushort* __restrict__ xTbf,
                                                  ushort* __restrict__ BcT,
                                                  ushort* __restrict__ VT) {
    cg::grid_group grid = cg::this_grid();
    const int bid = blockIdx.x;
    const int tid = threadIdx.x;
    const int w   = tid >> 6, l = tid & 63;

    __shared__ __align__(16) ushort T[32][264];
    __shared__ float sred[4], sred2[4];

    // ---------- prep: xbf, xTbf (one x read), BcT0 = bf16(W/NR) ----------
    if (bid < K1 / 32) {
        const int k0 = bid * 32;
        #pragma unroll
        for (int j = 0; j < 8; ++j) {
            int f  = j * 256 + tid;
            int b  = f >> 3;
            int i4 = f & 7;
            float4 v = *reinterpret_cast<const float4*>(x + (size_t)b * K1 + k0 + i4 * 4);
            ushort bv[4] = { f2bf(v.x), f2bf(v.y), f2bf(v.z), f2bf(v.w) };
            T[i4 * 4 + 0][b] = bv[0];
            T[i4 * 4 + 1][b] = bv[1];
            T[i4 * 4 + 2][b] = bv[2];
            T[i4 * 4 + 3][b] = bv[3];
            *reinterpret_cast<ushort4*>(xbf + (size_t)b * K1 + k0 + i4 * 4) =
                make_ushort4(bv[0], bv[1], bv[2], bv[3]);
        }
        __syncthreads();
        #pragma unroll
        for (int j = 0; j < 4; ++j) {
            int g   = j * 256 + tid;
            int row = g >> 5;
            int q8  = g & 31;
            *reinterpret_cast<uint4*>(xTbf + (size_t)(k0 + row) * NB + q8 * 8) =
                *reinterpret_cast<const uint4*>(&T[row][q8 * 8]);
        }
    }
    {
        const float cr0 = 1.0f / NR;
        for (size_t e = (size_t)bid * 256 + tid; e < (size_t)NR * NC * NO;
             e += (size_t)GRID * 256) {
            int o  = (int)(e & 15);
            int rc = (int)(e >> 4);
            int c  = rc % NC;
            int r  = rc / NC;
            float4 v0 = *reinterpret_cast<const float4*>(W + e * 8);
            float4 v1 = *reinterpret_cast<const float4*>(W + e * 8 + 4);
            ushort ob[8] = { f2bf(v0.x * cr0), f2bf(v0.y * cr0), f2bf(v0.z * cr0), f2bf(v0.w * cr0),
                             f2bf(v1.x * cr0), f2bf(v1.y * cr0), f2bf(v1.z * cr0), f2bf(v1.w * cr0) };
            *reinterpret_cast<uint4*>(BcT + (size_t)(c * NO + o) * K1 + r * 8) =
                *reinterpret_cast<uint4*>(ob);
        }
    }
    grid.sync();

    for (int it = 0; it < 3; ++it) {
        // ---- Phase A: GEMM1 split-K. 5760 wave-jobs of 8 mfma ----
        for (int j = bid * 4 + w; j < 16 * NC * KS; j += GRID * 4) {
            const int ksj = j % KS;
            const int t2  = j / KS;
            const int ct  = t2 % NC;
            const int mt  = t2 / NC;
            const ushort* ap = xbf + (size_t)(mt * 16 + (l & 15)) * K1 + ksj * KC + 8 * (l >> 4);
            const ushort* bp = BcT + (size_t)(ct * 16 + (l & 15)) * K1 + ksj * KC + 8 * (l >> 4);
            f32x4 acc = {0.f, 0.f, 0.f, 0.f};
            #pragma unroll
            for (int kk = 0; kk < KC / 32; ++kk) {
                s16x8 a = *reinterpret_cast<const s16x8*>(ap + kk * 32);
                s16x8 b = *reinterpret_cast<const s16x8*>(bp + kk * 32);
                acc = __builtin_amdgcn_mfma_f32_16x16x32_bf16(a, b, acc, 0, 0, 0);
            }
            float* sp = spart + (size_t)ksj * (NB * NN)
                      + (size_t)(mt * 16 + 4 * (l >> 4)) * NN + ct * 16 + (l & 15);
            #pragma unroll
            for (int q = 0; q < 4; ++q) sp[(size_t)q * NN] = acc[q];
        }
        grid.sync();

        // ---- Phase B: reduce split-K + squash -> VT (or out on final) ----
        for (int f = bid * 256 + tid; f < NB * NN; f += GRID * 256) {
            float s = 0.0f;
            #pragma unroll
            for (int ks = 0; ks < KS; ++ks) s += spart[(size_t)ks * (NB * NN) + f];
            float v = s * fabsf(s) / (1.0f + s * s);
            if (it == 2) {
                out[f] = v;
            } else {
                int b  = f / NN;
                int co = f - b * NN;
                VT[(size_t)co * NB + b] = f2bf(v);
            }
        }
        if (it == 2) break;
        grid.sync();

        // ---- Phase C: GEMM2 + W-contraction -> bbuf. 5760 wave-jobs ----
        for (int j = bid * 4 + w; j < (K1 / 16) * NC; j += GRID * 4) {
            const int ct = j % NC;
            const int mt = j / NC;
            const int m0 = mt * 16;
            const ushort* ap = xTbf + (size_t)(m0 + (l & 15)) * NB + 8 * (l >> 4);
            const ushort* bp = VT   + (size_t)(ct * 16 + (l & 15)) * NB + 8 * (l >> 4);
            f32x4 acc = {0.f, 0.f, 0.f, 0.f};
            #pragma unroll
            for (int kk = 0; kk < NB / 32; ++kk) {
                s16x8 a = *reinterpret_cast<const s16x8*>(ap + kk * 32);
                s16x8 b = *reinterpret_cast<const s16x8*>(bp + kk * 32);
                acc = __builtin_amdgcn_mfma_f32_16x16x32_bf16(a, b, acc, 0, 0, 0);
            }
            const int h  = l >> 4, o = l & 15;
            const int r  = (m0 >> 3) + (h >> 1);
            const int i0 = (4 * h) & 7;
            const float4 w4 = *reinterpret_cast<const float4*>(
                W + (((size_t)r * NC + ct) * NO + o) * NI + i0);
            float s = acc[0] * w4.x + acc[1] * w4.y + acc[2] * w4.z + acc[3] * w4.w;
            s += __shfl_xor(s, 1);
            s += __shfl_xor(s, 2);
            s += __shfl_xor(s, 4);
            s += __shfl_xor(s, 8);
            s += __shfl_xor(s, 16);
            if (l == 0 || l == 32) {
                int rr = (m0 >> 3) + (l >> 5);
                float val = s * (1.0f / NB);
                if (it > 0) bbuf[(size_t)rr * NC + ct] += val;
                else        bbuf[(size_t)rr * NC + ct] = val;
            }
        }
        grid.sync();

        // ---- Phase D: softmax over r (redundant per 8 blocks) + BcT ----
        for (int j = bid; j < 80; j += GRID) {
            const int c  = j >> 3;
            const int rs = j & 7;
            float m = -1e30f;
            for (int r = tid; r < NR; r += 256) m = fmaxf(m, bbuf[r * NC + c]);
            #pragma unroll
            for (int off = 1; off < 64; off <<= 1) m = fmaxf(m, __shfl_xor(m, off));
            if (l == 0) sred[w] = m;
            __syncthreads();
            m = fmaxf(fmaxf(sred[0], sred[1]), fmaxf(sred[2], sred[3]));

            float s = 0.0f;
            for (int r = tid; r < NR; r += 256) s += expf(bbuf[r * NC + c] - m);
            #pragma unroll
            for (int off = 1; off < 64; off <<= 1) s += __shfl_xor(s, off);
            if (l == 0) sred2[w] = s;
            __syncthreads();
            s = sred2[0] + sred2[1] + sred2[2] + sred2[3];
            const float inv = 1.0f / s;

            for (int e = tid; e < NO * 144; e += 256) {
                int o  = e / 144;
                int rr = e - o * 144;
                int r  = rs * 144 + rr;
                float cr = expf(bbuf[r * NC + c] - m) * inv;
                const float4* wp = reinterpret_cast<const float4*>(
                    W + (((size_t)r * NC + c) * NO + o) * NI);
                float4 v0 = wp[0];
                float4 v1 = wp[1];
                ushort ob[8] = { f2bf(v0.x * cr), f2bf(v0.y * cr), f2bf(v0.z * cr), f2bf(v0.w * cr),
                                 f2bf(v1.x * cr), f2bf(v1.y * cr), f2bf(v1.z * cr), f2bf(v1.w * cr) };
                *reinterpret_cast<uint4*>(BcT + (size_t)(c * NO + o) * K1 + r * 8) =
                    *reinterpret_cast<uint4*>(ob);
            }
        }
        grid.sync();
    }
}

extern "C" void kernel_launch(void* const* d_in, const int* in_sizes, int n_in,
                              void* d_out, int out_size, void* d_ws, size_t ws_size,
                              hipStream_t stream) {
    const float* x = (const float*)d_in[0];   // [256][9216]
    const float* W = (const float*)d_in[1];   // [1152,10,16,8]
    float* out = (float*)d_out;               // [256][160]

    // ws: bbuf | spart | xbf | xTbf | BcT | VT  (~18.4 MB)
    float*  bbuf  = (float*)d_ws;                          // 11520 f
    float*  spart = bbuf + (size_t)NR * NC;                // 36*40960 f = 5.90 MB
    ushort* xbf   = (ushort*)(spart + (size_t)KS * NB * NN);
    ushort* xTbf  = xbf + (size_t)NB * K1;                 // 4.72 MB each
    ushort* BcT   = xTbf + (size_t)K1 * NB;                // 2.95 MB
    ushort* VT    = BcT + (size_t)NN * K1;                 // 80 KB

    void* args[] = { (void*)&x, (void*)&W, (void*)&out, (void*)&bbuf, (void*)&spart,
                     (void*)&xbf, (void*)&xTbf, (void*)&BcT, (void*)&VT };
    hipLaunchCooperativeKernel((void*)k_fused, dim3(GRID), dim3(256), args, 0, stream);
}

// Round 11
// 102.310 us; speedup vs baseline: 6.8232x; 6.8232x over previous
//
#include <hip/hip_runtime.h>
#include <math.h>

namespace {
constexpr int NB = 256;    // batch
constexpr int NR = 1152;   // routes
constexpr int NC = 10;     // output capsules
constexpr int NO = 16;     // output dim
constexpr int NI = 8;      // input dim
constexpr int K1 = NR * NI;   // 9216
constexpr int NN = NC * NO;   // 160
constexpr int KS = 4;         // GEMM1 split-K across blocks
constexpr int KC = K1 / KS;   // 2304 per block (288 r)
constexpr int RCB = KC / NI;  // 288 r per K-slice
}

using s16x8 = __attribute__((ext_vector_type(8))) short;
using f32x4 = __attribute__((ext_vector_type(4))) float;

__device__ __forceinline__ ushort f2bf(float f) {
    uint u = __float_as_uint(f);
    uint r = (u + 0x7FFFu + ((u >> 16) & 1u)) >> 16;
    return (ushort)r;
}
__device__ __forceinline__ float bf2f(ushort v) {
    return __uint_as_float(((uint)v) << 16);
}

// prep: xbf[b][k], xTbf[k][b] (one x read, LDS transpose), WbT = bf16(W) [co][k]
__global__ __launch_bounds__(256) void k_prep(const float* __restrict__ x,
                                              const float* __restrict__ W,
                                              ushort* __restrict__ xbf,
                                              ushort* __restrict__ xTbf,
                                              ushort* __restrict__ WbT) {
    __shared__ __align__(16) ushort T[32][264];
    const int k0 = blockIdx.x * 32;          // 288 blocks cover K1
    #pragma unroll
    for (int j = 0; j < 8; ++j) {
        int f  = j * 256 + threadIdx.x;      // [0,2048)
        int b  = f >> 3;
        int i4 = f & 7;
        float4 v = *reinterpret_cast<const float4*>(x + (size_t)b * K1 + k0 + i4 * 4);
        ushort bv[4] = { f2bf(v.x), f2bf(v.y), f2bf(v.z), f2bf(v.w) };
        T[i4 * 4 + 0][b] = bv[0];
        T[i4 * 4 + 1][b] = bv[1];
        T[i4 * 4 + 2][b] = bv[2];
        T[i4 * 4 + 3][b] = bv[3];
        *reinterpret_cast<ushort4*>(xbf + (size_t)b * K1 + k0 + i4 * 4) =
            make_ushort4(bv[0], bv[1], bv[2], bv[3]);
    }
    __syncthreads();
    #pragma unroll
    for (int j = 0; j < 4; ++j) {
        int g   = j * 256 + threadIdx.x;     // [0,1024)
        int row = g >> 5;
        int q8  = g & 31;
        *reinterpret_cast<uint4*>(xTbf + (size_t)(k0 + row) * NB + q8 * 8) =
            *reinterpret_cast<const uint4*>(&T[row][q8 * 8]);
    }
    // WbT: 184320 (r,c,o) rows of 8, grid-stride, UNscaled
    for (size_t e = (size_t)blockIdx.x * 256 + threadIdx.x; e < (size_t)NR * NC * NO;
         e += (size_t)288 * 256) {
        int o  = (int)(e & 15);
        int rc = (int)(e >> 4);
        int c  = rc % NC;
        int r  = rc / NC;
        float4 v0 = *reinterpret_cast<const float4*>(W + e * 8);
        float4 v1 = *reinterpret_cast<const float4*>(W + e * 8 + 4);
        ushort ob[8] = { f2bf(v0.x), f2bf(v0.y), f2bf(v0.z), f2bf(v0.w),
                         f2bf(v1.x), f2bf(v1.y), f2bf(v1.z), f2bf(v1.w) };
        *reinterpret_cast<uint4*>(WbT + (size_t)(c * NO + o) * K1 + r * 8) =
            *reinterpret_cast<uint4*>(ob);
    }
}

// K_a: GEMM1 K-slice with on-the-fly c[r,c] scaling of B; redundant softmax.
// Grid (16 mt, 10 c, 4 ks) = 640 blocks, 4 waves (in-block K sub-split),
// LDS-reduce -> spart[ks][b][co].
__global__ __launch_bounds__(256) void k_a(const ushort* __restrict__ xbf,
                                           const ushort* __restrict__ WbT,
                                           const float* __restrict__ bbuf,
                                           float* __restrict__ spart,
                                           int first) {
    const int m0 = blockIdx.x * 16;
    const int c  = blockIdx.y;
    const int ks = blockIdx.z;
    const int tid = threadIdx.x;
    const int w = tid >> 6, l = tid & 63;

    __shared__ float crs[RCB];
    __shared__ float sred[4], sred2[4];
    __shared__ float red[4][16][16];

    if (first) {
        for (int i = tid; i < RCB; i += 256) crs[i] = 1.0f / NR;
    } else {
        // redundant softmax stats over r for column c (identical in all blocks)
        float m = -1e30f;
        for (int r = tid; r < NR; r += 256) m = fmaxf(m, bbuf[r * NC + c]);
        #pragma unroll
        for (int off = 1; off < 64; off <<= 1) m = fmaxf(m, __shfl_xor(m, off));
        if (l == 0) sred[w] = m;
        __syncthreads();
        m = fmaxf(fmaxf(sred[0], sred[1]), fmaxf(sred[2], sred[3]));
        float s = 0.0f;
        for (int r = tid; r < NR; r += 256) s += expf(bbuf[r * NC + c] - m);
        #pragma unroll
        for (int off = 1; off < 64; off <<= 1) s += __shfl_xor(s, off);
        if (l == 0) sred2[w] = s;
        __syncthreads();
        s = sred2[0] + sred2[1] + sred2[2] + sred2[3];
        const float inv = 1.0f / s;
        const int r0 = ks * RCB;
        for (int i = tid; i < RCB; i += 256)
            crs[i] = expf(bbuf[(r0 + i) * NC + c] - m) * inv;
    }
    __syncthreads();

    const int kb = ks * KC + w * (KC / 4);       // wave K sub-slice (576)
    const ushort* ap = xbf + (size_t)(m0 + (l & 15)) * K1 + kb + 8 * (l >> 4);
    const ushort* bp = WbT + (size_t)(c * NO + (l & 15)) * K1 + kb + 8 * (l >> 4);

    f32x4 acc = {0.f, 0.f, 0.f, 0.f};
    #pragma unroll
    for (int kk = 0; kk < KC / 4 / 32; ++kk) {   // 18
        s16x8 a    = *reinterpret_cast<const s16x8*>(ap + kk * 32);
        s16x8 braw = *reinterpret_cast<const s16x8*>(bp + kk * 32);
        const float cr = crs[w * 72 + kk * 4 + (l >> 4)];
        s16x8 b;
        #pragma unroll
        for (int e = 0; e < 8; ++e) {
            float f = bf2f((ushort)braw[e]) * cr;
            b[e] = (short)f2bf(f);
        }
        acc = __builtin_amdgcn_mfma_f32_16x16x32_bf16(a, b, acc, 0, 0, 0);
    }

    #pragma unroll
    for (int q = 0; q < 4; ++q) red[w][4 * (l >> 4) + q][l & 15] = acc[q];
    __syncthreads();
    const int row = tid >> 4, col = tid & 15;
    float s = red[0][row][col] + red[1][row][col] + red[2][row][col] + red[3][row][col];
    spart[(size_t)ks * (NB * NN) + (size_t)(m0 + row) * NN + c * NO + col] = s;
}

// K_b: [sum spart -> squash -> v (LDS or out)] + GEMM2-from-LDS + W-contract
// -> exclusive bbuf update. Grid (36,10) = 360 blocks; final: (1,10).
__global__ __launch_bounds__(256) void k_b(const ushort* __restrict__ xTbf,
                                           const float* __restrict__ spart,
                                           const float* __restrict__ W,
                                           float* __restrict__ bbuf,
                                           float* __restrict__ out,
                                           int it, int final_pass) {
    const int c = blockIdx.y;
    const int tid = threadIdx.x;
    const int w = tid >> 6, l = tid & 63;

    __shared__ __align__(16) ushort VT[16][264];

    for (int f = tid; f < NB * NO; f += 256) {   // 4096 (b,oo)
        int b  = f >> 4;
        int oo = f & 15;
        size_t idx = (size_t)b * NN + c * NO + oo;
        float s = spart[idx] + spart[(size_t)1 * NB * NN + idx]
                + spart[(size_t)2 * NB * NN + idx] + spart[(size_t)3 * NB * NN + idx];
        float v = s * fabsf(s) / (1.0f + s * s);
        if (final_pass) out[idx] = v;
        else            VT[oo][b] = f2bf(v);
    }
    if (final_pass) return;
    __syncthreads();

    #pragma unroll
    for (int t = 0; t < 4; ++t) {
        const int mt = blockIdx.x * 16 + w * 4 + t;   // 0..575
        const int m0 = mt * 16;
        const ushort* ap = xTbf + (size_t)(m0 + (l & 15)) * NB + 8 * (l >> 4);
        f32x4 acc = {0.f, 0.f, 0.f, 0.f};
        #pragma unroll
        for (int kk = 0; kk < NB / 32; ++kk) {
            s16x8 a = *reinterpret_cast<const s16x8*>(ap + kk * 32);
            s16x8 b = *reinterpret_cast<const s16x8*>(&VT[l & 15][32 * kk + 8 * (l >> 4)]);
            acc = __builtin_amdgcn_mfma_f32_16x16x32_bf16(a, b, acc, 0, 0, 0);
        }
        const int h  = l >> 4, o = l & 15;
        const int r  = (m0 >> 3) + (h >> 1);
        const int i0 = (4 * h) & 7;
        const float4 w4 = *reinterpret_cast<const float4*>(
            W + (((size_t)r * NC + c) * NO + o) * NI + i0);
        float s = acc[0] * w4.x + acc[1] * w4.y + acc[2] * w4.z + acc[3] * w4.w;
        s += __shfl_xor(s, 1);
        s += __shfl_xor(s, 2);
        s += __shfl_xor(s, 4);
        s += __shfl_xor(s, 8);
        s += __shfl_xor(s, 16);
        if (l == 0 || l == 32) {
            int rr = (m0 >> 3) + (l >> 5);
            float val = s * (1.0f / NB);
            if (it > 0) bbuf[(size_t)rr * NC + c] += val;
            else        bbuf[(size_t)rr * NC + c] = val;
        }
    }
}

extern "C" void kernel_launch(void* const* d_in, const int* in_sizes, int n_in,
                              void* d_out, int out_size, void* d_ws, size_t ws_size,
                              hipStream_t stream) {
    const float* x = (const float*)d_in[0];   // [256][9216]
    const float* W = (const float*)d_in[1];   // [1152,10,16,8]
    float* out = (float*)d_out;               // [256][160]

    // ws: spart | bbuf | xbf | xTbf | WbT  (~13.1 MB)
    float*  spart = (float*)d_ws;                          // 4*40960 f = 655 KB
    float*  bbuf  = spart + (size_t)KS * NB * NN;          // 11520 f
    ushort* xbf   = (ushort*)(bbuf + (size_t)NR * NC);     // 4.72 MB
    ushort* xTbf  = xbf + (size_t)NB * K1;                 // 4.72 MB
    ushort* WbT   = xTbf + (size_t)K1 * NB;                // 2.95 MB

    k_prep<<<K1 / 32, 256, 0, stream>>>(x, W, xbf, xTbf, WbT);   // 288 blocks

    dim3 ga(NB / 16, NC, KS);   // (16,10,4) = 640 blocks
    dim3 gb(36, NC);            // 360 blocks
    dim3 gbf(1, NC);            // final squash->out

    for (int it = 0; it < 3; ++it) {
        k_a<<<ga, 256, 0, stream>>>(xbf, WbT, bbuf, spart, it == 0 ? 1 : 0);
        if (it < 2)
            k_b<<<gb, 256, 0, stream>>>(xTbf, spart, W, bbuf, nullptr, it, 0);
        else
            k_b<<<gbf, 256, 0, stream>>>(xTbf, spart, W, bbuf, out, it, 1);
    }
}

// Round 12
// 91.019 us; speedup vs baseline: 7.6697x; 1.1241x over previous
//
#include <hip/hip_runtime.h>
#include <math.h>

namespace {
constexpr int NB = 256;    // batch
constexpr int NR = 1152;   // routes
constexpr int NC = 10;     // output capsules
constexpr int NO = 16;     // output dim
constexpr int NI = 8;      // input dim
constexpr int K1 = NR * NI;   // 9216
constexpr int NN = NC * NO;   // 160
constexpr int KS = 8;         // GEMM1 split-K slices (across blocks)
constexpr int KC = K1 / KS;   // 1152 per block
constexpr int RPB = NR / KS;  // 144 r per block
}

using s16x8 = __attribute__((ext_vector_type(8))) short;
using f32x4 = __attribute__((ext_vector_type(4))) float;

__device__ __forceinline__ ushort f2bf(float f) {
    uint u = __float_as_uint(f);
    uint r = (u + 0x7FFFu + ((u >> 16) & 1u)) >> 16;
    return (ushort)r;
}

__device__ __forceinline__ s16x8 pack8(float4 a0, float4 a1) {
    s16x8 r;
    r[0] = (short)f2bf(a0.x); r[1] = (short)f2bf(a0.y);
    r[2] = (short)f2bf(a0.z); r[3] = (short)f2bf(a0.w);
    r[4] = (short)f2bf(a1.x); r[5] = (short)f2bf(a1.y);
    r[6] = (short)f2bf(a1.z); r[7] = (short)f2bf(a1.w);
    return r;
}

__device__ __forceinline__ s16x8 pack8s(float4 a0, float4 a1, float cr) {
    s16x8 r;
    r[0] = (short)f2bf(a0.x * cr); r[1] = (short)f2bf(a0.y * cr);
    r[2] = (short)f2bf(a0.z * cr); r[3] = (short)f2bf(a0.w * cr);
    r[4] = (short)f2bf(a1.x * cr); r[5] = (short)f2bf(a1.y * cr);
    r[6] = (short)f2bf(a1.z * cr); r[7] = (short)f2bf(a1.w * cr);
    return r;
}

// GEMM1 K-slice: A = bf16(x) on the fly, B = bf16(c[r,c]*W) on the fly.
// Grid (16 mt, 10 c, 8 ks); 4 waves sub-split K (288 each, 9 mfma).
// FIRST: c=1/NR constant, and blocks with flat id<288 also write one
// xT-transpose tile (consumed only by the NEXT kernel, k_b).
template <bool FIRST>
__global__ __launch_bounds__(256) void k_a(const float* __restrict__ x,
                                           const float* __restrict__ W,
                                           const float* __restrict__ bbuf,
                                           float* __restrict__ spart,
                                           ushort* __restrict__ xTbf) {
    const int m0 = blockIdx.x * 16;
    const int c  = blockIdx.y;
    const int ks = blockIdx.z;
    const int tid = threadIdx.x;
    const int w = tid >> 6, l = tid & 63;

    __shared__ float red[4][16][16];
    __shared__ float crs[RPB];
    __shared__ float sred[4], sred2[4];

    if constexpr (FIRST) {
        __shared__ __align__(16) ushort T[32][264];
        const int bid = blockIdx.x + 16 * blockIdx.y + 160 * blockIdx.z;
        if (bid < K1 / 32) {
            const int k0 = bid * 32;
            #pragma unroll
            for (int j = 0; j < 8; ++j) {
                int f  = j * 256 + tid;
                int b  = f >> 3;
                int i4 = f & 7;
                float4 v = *reinterpret_cast<const float4*>(
                    x + (size_t)b * K1 + k0 + i4 * 4);
                T[i4 * 4 + 0][b] = f2bf(v.x);
                T[i4 * 4 + 1][b] = f2bf(v.y);
                T[i4 * 4 + 2][b] = f2bf(v.z);
                T[i4 * 4 + 3][b] = f2bf(v.w);
            }
            __syncthreads();
            #pragma unroll
            for (int j = 0; j < 4; ++j) {
                int g   = j * 256 + tid;
                int row = g >> 5;
                int q8  = g & 31;
                *reinterpret_cast<uint4*>(xTbf + (size_t)(k0 + row) * NB + q8 * 8) =
                    *reinterpret_cast<const uint4*>(&T[row][q8 * 8]);
            }
        }
    } else {
        // softmax stats over full column c (identical in all blocks), then
        // crs for this block's 144 r's.
        float m = -1e30f;
        for (int r = tid; r < NR; r += 256) m = fmaxf(m, bbuf[r * NC + c]);
        #pragma unroll
        for (int off = 1; off < 64; off <<= 1) m = fmaxf(m, __shfl_xor(m, off));
        if (l == 0) sred[w] = m;
        __syncthreads();
        m = fmaxf(fmaxf(sred[0], sred[1]), fmaxf(sred[2], sred[3]));
        float s = 0.0f;
        for (int r = tid; r < NR; r += 256) s += expf(bbuf[r * NC + c] - m);
        #pragma unroll
        for (int off = 1; off < 64; off <<= 1) s += __shfl_xor(s, off);
        if (l == 0) sred2[w] = s;
        __syncthreads();
        s = sred2[0] + sred2[1] + sred2[2] + sred2[3];
        const float inv = 1.0f / s;
        for (int i = tid; i < RPB; i += 256)
            crs[i] = expf(bbuf[(ks * RPB + i) * NC + c] - m) * inv;
        __syncthreads();
    }

    const int kb = ks * KC + w * (KC / 4);   // wave K base (288 per wave)
    const int lg = l >> 4;
    const float* ap = x + (size_t)(m0 + (l & 15)) * K1 + kb + 8 * lg;

    f32x4 acc = {0.f, 0.f, 0.f, 0.f};
    #pragma unroll
    for (int kk = 0; kk < KC / 4 / 32; ++kk) {   // 9
        const int k = kb + kk * 32 + 8 * lg;
        const int r = k >> 3;
        float4 a0 = *reinterpret_cast<const float4*>(ap + kk * 32);
        float4 a1 = *reinterpret_cast<const float4*>(ap + kk * 32 + 4);
        const float* wp = W + (((size_t)r * NC + c) * NO + (l & 15)) * NI;
        float4 b0 = *reinterpret_cast<const float4*>(wp);
        float4 b1 = *reinterpret_cast<const float4*>(wp + 4);
        const float cr = FIRST ? (1.0f / NR) : crs[r - ks * RPB];
        s16x8 a = pack8(a0, a1);
        s16x8 b = pack8s(b0, b1, cr);
        acc = __builtin_amdgcn_mfma_f32_16x16x32_bf16(a, b, acc, 0, 0, 0);
    }

    #pragma unroll
    for (int q = 0; q < 4; ++q) red[w][4 * lg + q][l & 15] = acc[q];
    __syncthreads();
    const int row = tid >> 4, col = tid & 15;
    float s2 = red[0][row][col] + red[1][row][col]
             + red[2][row][col] + red[3][row][col];
    spart[(size_t)ks * (NB * NN) + (size_t)(m0 + row) * NN + c * NO + col] = s2;
}

// K_b: [sum spart -> squash -> VT in LDS] + GEMM2-from-LDS + W-contract ->
// exclusive bbuf update. Grid (36,10).
__global__ __launch_bounds__(256) void k_b(const ushort* __restrict__ xTbf,
                                           const float* __restrict__ spart,
                                           const float* __restrict__ W,
                                           float* __restrict__ bbuf,
                                           int it) {
    const int c = blockIdx.y;
    const int tid = threadIdx.x;
    const int w = tid >> 6, l = tid & 63;

    __shared__ __align__(16) ushort VT[16][264];

    for (int f = tid; f < NB * NO; f += 256) {   // 4096 (b,oo)
        int b  = f >> 4;
        int oo = f & 15;
        size_t idx = (size_t)b * NN + c * NO + oo;
        float s = 0.0f;
        #pragma unroll
        for (int ks = 0; ks < KS; ++ks) s += spart[(size_t)ks * NB * NN + idx];
        float v = s * fabsf(s) / (1.0f + s * s);
        VT[oo][b] = f2bf(v);
    }
    __syncthreads();

    #pragma unroll
    for (int t = 0; t < 4; ++t) {
        const int mt = blockIdx.x * 16 + w * 4 + t;   // 0..575
        const int m0 = mt * 16;
        const ushort* ap = xTbf + (size_t)(m0 + (l & 15)) * NB + 8 * (l >> 4);
        f32x4 acc = {0.f, 0.f, 0.f, 0.f};
        #pragma unroll
        for (int kk = 0; kk < NB / 32; ++kk) {
            s16x8 a = *reinterpret_cast<const s16x8*>(ap + kk * 32);
            s16x8 b = *reinterpret_cast<const s16x8*>(&VT[l & 15][32 * kk + 8 * (l >> 4)]);
            acc = __builtin_amdgcn_mfma_f32_16x16x32_bf16(a, b, acc, 0, 0, 0);
        }
        const int h  = l >> 4, o = l & 15;
        const int r  = (m0 >> 3) + (h >> 1);
        const int i0 = (4 * h) & 7;
        const float4 w4 = *reinterpret_cast<const float4*>(
            W + (((size_t)r * NC + c) * NO + o) * NI + i0);
        float s = acc[0] * w4.x + acc[1] * w4.y + acc[2] * w4.z + acc[3] * w4.w;
        s += __shfl_xor(s, 1);
        s += __shfl_xor(s, 2);
        s += __shfl_xor(s, 4);
        s += __shfl_xor(s, 8);
        s += __shfl_xor(s, 16);
        if (l == 0 || l == 32) {
            int rr = (m0 >> 3) + (l >> 5);
            float val = s * (1.0f / NB);
            if (it > 0) bbuf[(size_t)rr * NC + c] += val;
            else        bbuf[(size_t)rr * NC + c] = val;
        }
    }
}

// final: sum spart slices + squash -> out[b][c][o]. Grid (16,10).
__global__ __launch_bounds__(256) void k_bf(const float* __restrict__ spart,
                                            float* __restrict__ out) {
    const int m0 = blockIdx.x * 16;
    const int c  = blockIdx.y;
    const int row = threadIdx.x >> 4, col = threadIdx.x & 15;
    size_t idx = (size_t)(m0 + row) * NN + c * NO + col;
    float s = 0.0f;
    #pragma unroll
    for (int ks = 0; ks < KS; ++ks) s += spart[(size_t)ks * NB * NN + idx];
    out[idx] = s * fabsf(s) / (1.0f + s * s);
}

extern "C" void kernel_launch(void* const* d_in, const int* in_sizes, int n_in,
                              void* d_out, int out_size, void* d_ws, size_t ws_size,
                              hipStream_t stream) {
    const float* x = (const float*)d_in[0];   // [256][9216]
    const float* W = (const float*)d_in[1];   // [1152,10,16,8]
    float* out = (float*)d_out;               // [256][160]

    // ws: spart | bbuf | xTbf  (~6.1 MB)
    float*  spart = (float*)d_ws;                          // 8*40960 f = 1.31 MB
    float*  bbuf  = spart + (size_t)KS * NB * NN;          // 11520 f
    ushort* xTbf  = (ushort*)(bbuf + (size_t)NR * NC);     // 9216*256 = 4.72 MB

    dim3 ga(NB / 16, NC, KS);   // (16,10,8) = 1280 blocks
    dim3 gb(36, NC);            // 360 blocks
    dim3 gf(NB / 16, NC);       // 160 blocks

    k_a<true><<<ga, 256, 0, stream>>>(x, W, nullptr, spart, xTbf);   // + xT prep
    k_b<<<gb, 256, 0, stream>>>(xTbf, spart, W, bbuf, 0);
    k_a<false><<<ga, 256, 0, stream>>>(x, W, bbuf, spart, nullptr);
    k_b<<<gb, 256, 0, stream>>>(xTbf, spart, W, bbuf, 1);
    k_a<false><<<ga, 256, 0, stream>>>(x, W, bbuf, spart, nullptr);
    k_bf<<<gf, 256, 0, stream>>>(spart, out);
}

// Round 13
// 88.339 us; speedup vs baseline: 7.9023x; 1.0303x over previous
//
#include <hip/hip_runtime.h>
#include <math.h>

namespace {
constexpr int NB = 256;    // batch
constexpr int NR = 1152;   // routes
constexpr int NC = 10;     // output capsules
constexpr int NO = 16;     // output dim
constexpr int NI = 8;      // input dim
constexpr int K1 = NR * NI;   // 9216
constexpr int NN = NC * NO;   // 160
constexpr int KS = 8;         // GEMM1 split-K slices (across blocks)
constexpr int KC = K1 / KS;   // 1152 per block
constexpr int RPB = NR / KS;  // 144 r per block
}

using s16x8 = __attribute__((ext_vector_type(8))) short;
using f32x4 = __attribute__((ext_vector_type(4))) float;

__device__ __forceinline__ ushort f2bf(float f) {
    uint u = __float_as_uint(f);
    uint r = (u + 0x7FFFu + ((u >> 16) & 1u)) >> 16;
    return (ushort)r;
}

__device__ __forceinline__ s16x8 pack8(float4 a0, float4 a1) {
    s16x8 r;
    r[0] = (short)f2bf(a0.x); r[1] = (short)f2bf(a0.y);
    r[2] = (short)f2bf(a0.z); r[3] = (short)f2bf(a0.w);
    r[4] = (short)f2bf(a1.x); r[5] = (short)f2bf(a1.y);
    r[6] = (short)f2bf(a1.z); r[7] = (short)f2bf(a1.w);
    return r;
}

__device__ __forceinline__ s16x8 pack8s(float4 a0, float4 a1, float cr) {
    s16x8 r;
    r[0] = (short)f2bf(a0.x * cr); r[1] = (short)f2bf(a0.y * cr);
    r[2] = (short)f2bf(a0.z * cr); r[3] = (short)f2bf(a0.w * cr);
    r[4] = (short)f2bf(a1.x * cr); r[5] = (short)f2bf(a1.y * cr);
    r[6] = (short)f2bf(a1.z * cr); r[7] = (short)f2bf(a1.w * cr);
    return r;
}

// GEMM1 K-slice. A = bf16(cr * x) on the fly (one r per A-fragment -> one cr).
// B: FIRST -> bf16(W fp32) on the fly; else -> direct bf16 load from Wb.
// Grid (16 mt, 10 c, 8 ks); 4 waves sub-split K (288 each, 9 mfma).
// FIRST also: flat id<288 write one xT tile; grid-stride pack Wb = bf16(W).
template <bool FIRST>
__global__ __launch_bounds__(256) void k_a(const float* __restrict__ x,
                                           const float* __restrict__ W,
                                           ushort* __restrict__ Wb,
                                           const float* __restrict__ bbuf,
                                           float* __restrict__ spart,
                                           ushort* __restrict__ xTbf) {
    const int m0 = blockIdx.x * 16;
    const int c  = blockIdx.y;
    const int ks = blockIdx.z;
    const int tid = threadIdx.x;
    const int w = tid >> 6, l = tid & 63;

    __shared__ float red[4][16][16];
    __shared__ float crs[RPB];
    __shared__ float sred[4], sred2[4];

    if constexpr (FIRST) {
        // xT prep (first 288 flat blocks)
        __shared__ __align__(16) ushort T[32][264];
        const int bid = blockIdx.x + 16 * blockIdx.y + 160 * blockIdx.z;
        if (bid < K1 / 32) {
            const int k0 = bid * 32;
            #pragma unroll
            for (int j = 0; j < 8; ++j) {
                int f  = j * 256 + tid;
                int b  = f >> 3;
                int i4 = f & 7;
                float4 v = *reinterpret_cast<const float4*>(
                    x + (size_t)b * K1 + k0 + i4 * 4);
                T[i4 * 4 + 0][b] = f2bf(v.x);
                T[i4 * 4 + 1][b] = f2bf(v.y);
                T[i4 * 4 + 2][b] = f2bf(v.z);
                T[i4 * 4 + 3][b] = f2bf(v.w);
            }
            __syncthreads();
            #pragma unroll
            for (int j = 0; j < 4; ++j) {
                int g   = j * 256 + tid;
                int row = g >> 5;
                int q8  = g & 31;
                *reinterpret_cast<uint4*>(xTbf + (size_t)(k0 + row) * NB + q8 * 8) =
                    *reinterpret_cast<const uint4*>(&T[row][q8 * 8]);
            }
        }
        // Wb = bf16(W), natural layout, grid-stride, coalesced
        const int nblk = 16 * NC * KS;
        for (size_t e = (size_t)(blockIdx.x + 16 * blockIdx.y + 160 * blockIdx.z) * 256 + tid;
             e < (size_t)NR * NC * NO; e += (size_t)nblk * 256) {
            float4 v0 = *reinterpret_cast<const float4*>(W + e * 8);
            float4 v1 = *reinterpret_cast<const float4*>(W + e * 8 + 4);
            s16x8 p = pack8(v0, v1);
            *reinterpret_cast<uint4*>(Wb + e * 8) = *reinterpret_cast<uint4*>(&p);
        }
    } else {
        // softmax stats over full column c (identical in all blocks) -> crs
        float m = -1e30f;
        for (int r = tid; r < NR; r += 256) m = fmaxf(m, bbuf[r * NC + c]);
        #pragma unroll
        for (int off = 1; off < 64; off <<= 1) m = fmaxf(m, __shfl_xor(m, off));
        if (l == 0) sred[w] = m;
        __syncthreads();
        m = fmaxf(fmaxf(sred[0], sred[1]), fmaxf(sred[2], sred[3]));
        float s = 0.0f;
        for (int r = tid; r < NR; r += 256) s += expf(bbuf[r * NC + c] - m);
        #pragma unroll
        for (int off = 1; off < 64; off <<= 1) s += __shfl_xor(s, off);
        if (l == 0) sred2[w] = s;
        __syncthreads();
        s = sred2[0] + sred2[1] + sred2[2] + sred2[3];
        const float inv = 1.0f / s;
        for (int i = tid; i < RPB; i += 256)
            crs[i] = expf(bbuf[(ks * RPB + i) * NC + c] - m) * inv;
        __syncthreads();
    }

    const int kb = ks * KC + w * (KC / 4);   // wave K base (288)
    const int lg = l >> 4;
    const float* ap = x + (size_t)(m0 + (l & 15)) * K1 + kb + 8 * lg;

    f32x4 acc = {0.f, 0.f, 0.f, 0.f};
    #pragma unroll
    for (int kk = 0; kk < KC / 4 / 32; ++kk) {   // 9
        const int k = kb + kk * 32 + 8 * lg;
        const int r = k >> 3;
        float4 a0 = *reinterpret_cast<const float4*>(ap + kk * 32);
        float4 a1 = *reinterpret_cast<const float4*>(ap + kk * 32 + 4);
        const float cr = FIRST ? (1.0f / NR) : crs[r - ks * RPB];
        s16x8 a = pack8s(a0, a1, cr);
        s16x8 b;
        if constexpr (FIRST) {
            const float* wp = W + ((size_t)r * NC + c) * 128 + (l & 15) * 8;
            b = pack8(*reinterpret_cast<const float4*>(wp),
                      *reinterpret_cast<const float4*>(wp + 4));
        } else {
            b = *reinterpret_cast<const s16x8*>(
                Wb + ((size_t)r * NC + c) * 128 + (l & 15) * 8);
        }
        acc = __builtin_amdgcn_mfma_f32_16x16x32_bf16(a, b, acc, 0, 0, 0);
    }

    #pragma unroll
    for (int q = 0; q < 4; ++q) red[w][4 * lg + q][l & 15] = acc[q];
    __syncthreads();
    const int row = tid >> 4, col = tid & 15;
    float s2 = red[0][row][col] + red[1][row][col]
             + red[2][row][col] + red[3][row][col];
    spart[(size_t)ks * (NB * NN) + (size_t)(m0 + row) * NN + c * NO + col] = s2;
}

// K_b: [sum spart -> squash -> VT in LDS] + GEMM2-from-LDS + W-contract ->
// exclusive bbuf update. Grid (36,10).
__global__ __launch_bounds__(256) void k_b(const ushort* __restrict__ xTbf,
                                           const float* __restrict__ spart,
                                           const float* __restrict__ W,
                                           float* __restrict__ bbuf,
                                           int it) {
    const int c = blockIdx.y;
    const int tid = threadIdx.x;
    const int w = tid >> 6, l = tid & 63;

    __shared__ __align__(16) ushort VT[16][264];

    for (int f = tid; f < NB * NO; f += 256) {   // 4096 (b,oo)
        int b  = f >> 4;
        int oo = f & 15;
        size_t idx = (size_t)b * NN + c * NO + oo;
        float s = 0.0f;
        #pragma unroll
        for (int ks = 0; ks < KS; ++ks) s += spart[(size_t)ks * NB * NN + idx];
        float v = s * fabsf(s) / (1.0f + s * s);
        VT[oo][b] = f2bf(v);
    }
    __syncthreads();

    #pragma unroll
    for (int t = 0; t < 4; ++t) {
        const int mt = blockIdx.x * 16 + w * 4 + t;   // 0..575
        const int m0 = mt * 16;
        const ushort* ap = xTbf + (size_t)(m0 + (l & 15)) * NB + 8 * (l >> 4);
        f32x4 acc = {0.f, 0.f, 0.f, 0.f};
        #pragma unroll
        for (int kk = 0; kk < NB / 32; ++kk) {
            s16x8 a = *reinterpret_cast<const s16x8*>(ap + kk * 32);
            s16x8 b = *reinterpret_cast<const s16x8*>(&VT[l & 15][32 * kk + 8 * (l >> 4)]);
            acc = __builtin_amdgcn_mfma_f32_16x16x32_bf16(a, b, acc, 0, 0, 0);
        }
        const int h  = l >> 4, o = l & 15;
        const int r  = (m0 >> 3) + (h >> 1);
        const int i0 = (4 * h) & 7;
        const float4 w4 = *reinterpret_cast<const float4*>(
            W + (((size_t)r * NC + c) * NO + o) * NI + i0);
        float s = acc[0] * w4.x + acc[1] * w4.y + acc[2] * w4.z + acc[3] * w4.w;
        s += __shfl_xor(s, 1);
        s += __shfl_xor(s, 2);
        s += __shfl_xor(s, 4);
        s += __shfl_xor(s, 8);
        s += __shfl_xor(s, 16);
        if (l == 0 || l == 32) {
            int rr = (m0 >> 3) + (l >> 5);
            float val = s * (1.0f / NB);
            if (it > 0) bbuf[(size_t)rr * NC + c] += val;
            else        bbuf[(size_t)rr * NC + c] = val;
        }
    }
}

// final: sum spart slices + squash -> out[b][c][o]. Grid (16,10).
__global__ __launch_bounds__(256) void k_bf(const float* __restrict__ spart,
                                            float* __restrict__ out) {
    const int m0 = blockIdx.x * 16;
    const int c  = blockIdx.y;
    const int row = threadIdx.x >> 4, col = threadIdx.x & 15;
    size_t idx = (size_t)(m0 + row) * NN + c * NO + col;
    float s = 0.0f;
    #pragma unroll
    for (int ks = 0; ks < KS; ++ks) s += spart[(size_t)ks * NB * NN + idx];
    out[idx] = s * fabsf(s) / (1.0f + s * s);
}

extern "C" void kernel_launch(void* const* d_in, const int* in_sizes, int n_in,
                              void* d_out, int out_size, void* d_ws, size_t ws_size,
                              hipStream_t stream) {
    const float* x = (const float*)d_in[0];   // [256][9216]
    const float* W = (const float*)d_in[1];   // [1152,10,16,8]
    float* out = (float*)d_out;               // [256][160]

    // ws: spart | bbuf | xTbf | Wb  (~9.1 MB)
    float*  spart = (float*)d_ws;                          // 8*40960 f = 1.31 MB
    float*  bbuf  = spart + (size_t)KS * NB * NN;          // 11520 f
    ushort* xTbf  = (ushort*)(bbuf + (size_t)NR * NC);     // 4.72 MB
    ushort* Wb    = xTbf + (size_t)K1 * NB;                // 2.95 MB

    dim3 ga(NB / 16, NC, KS);   // (16,10,8) = 1280 blocks
    dim3 gb(36, NC);            // 360 blocks
    dim3 gf(NB / 16, NC);       // 160 blocks

    k_a<true><<<ga, 256, 0, stream>>>(x, W, Wb, nullptr, spart, xTbf);
    k_b<<<gb, 256, 0, stream>>>(xTbf, spart, W, bbuf, 0);
    k_a<false><<<ga, 256, 0, stream>>>(x, W, Wb, bbuf, spart, nullptr);
    k_b<<<gb, 256, 0, stream>>>(xTbf, spart, W, bbuf, 1);
    k_a<false><<<ga, 256, 0, stream>>>(x, W, Wb, bbuf, spart, nullptr);
    k_bf<<<gf, 256, 0, stream>>>(spart, out);
}